// Round 1
// baseline (780.578 us; speedup 1.0000x reference)
//
#include <hip/hip_runtime.h>
#include <hip/hip_bf16.h>

// Reference: h[b] = dot(x[b,0,0:8], weight[0:8]) + bias   (weight_y term is zero)
// x: (65536, 365, 8) f32 ; weight: (8,1) f32 ; bias: (1,) f32 ; out: (65536,1) f32

#define BATCH 65536
#define SEQ 365
#define ISZ 8

__global__ __launch_bounds__(256) void leafriver_kernel(
    const float* __restrict__ x,
    const float* __restrict__ weight,
    const float* __restrict__ bias,
    float* __restrict__ out)
{
    int b = blockIdx.x * blockDim.x + threadIdx.x;
    if (b >= BATCH) return;

    // x[b, 0, :] starts at b * SEQ * ISZ floats; byte offset b*11680 is 16B-aligned.
    const float4* xp = reinterpret_cast<const float4*>(x + (size_t)b * (SEQ * ISZ));
    float4 x0 = xp[0];
    float4 x1 = xp[1];

    // weight is tiny (8 floats) — broadcast from cache.
    const float4* wp = reinterpret_cast<const float4*>(weight);
    float4 w0 = wp[0];
    float4 w1 = wp[1];

    float acc = x0.x * w0.x + x0.y * w0.y + x0.z * w0.z + x0.w * w0.w
              + x1.x * w1.x + x1.y * w1.y + x1.z * w1.z + x1.w * w1.w;

    out[b] = acc + bias[0];
}

extern "C" void kernel_launch(void* const* d_in, const int* in_sizes, int n_in,
                              void* d_out, int out_size, void* d_ws, size_t ws_size,
                              hipStream_t stream) {
    const float* x      = (const float*)d_in[0];
    const float* weight = (const float*)d_in[1];
    // d_in[2] is weight_y (unused — multiplied by zeros in the reference)
    const float* bias   = (const float*)d_in[3];
    float* out = (float*)d_out;

    dim3 block(256);
    dim3 grid((BATCH + 255) / 256);
    leafriver_kernel<<<grid, block, 0, stream>>>(x, weight, bias, out);
}